// Round 4
// baseline (2501.500 us; speedup 1.0000x reference)
//
#include <hip/hip_runtime.h>
#include <cstdint>
#include <cstddef>

#define B_GRAPHS 2048
#define N_NODES  64
#define FIN      49
#define D_DIM    256
#define H_HEADS  8
#define DK_DIM   32
#define L_LAYERS 6
#define FC_DIM   128
#define ALPHA    0.2f

#define M_FULL     (B_GRAPHS * N_NODES)           // 131072 rows

typedef __bf16 bf16x8 __attribute__((ext_vector_type(8)));
typedef float  f32x4  __attribute__((ext_vector_type(4)));

#define MFMA16(a, b, c) __builtin_amdgcn_mfma_f32_16x16x32_bf16(a, b, c, 0, 0, 0)

// LDS byte offset for (row, 16B-slot), slot-swizzled within row (64B rows).
__device__ __forceinline__ int swz(int r, int s) {
    return r * 64 + (((s ^ (r & 3)) << 4));
}

// ---------------------------------------------------------------------------
// Weight split: W -> bf16 hi/lo. gat_W is [l][n][k] row-major (K-minor).
// W_emb [256][49] padded to [256][64].
// ---------------------------------------------------------------------------
__global__ void convert_weights(const float* __restrict__ W_emb,
                                const float* __restrict__ gat_W,
                                __bf16* __restrict__ Whi_emb,  // [256][64]
                                __bf16* __restrict__ Wlo_emb,
                                __bf16* __restrict__ Whi,      // [6][256][256]
                                __bf16* __restrict__ Wlo)
{
    int idx = blockIdx.x * 256 + threadIdx.x;
    if (idx < 256 * 64) {
        int n = idx >> 6, k = idx & 63;
        float f = (k < FIN) ? W_emb[n * FIN + k] : 0.f;
        __bf16 hi = (__bf16)f;
        Whi_emb[idx] = hi;
        Wlo_emb[idx] = (__bf16)(f - (float)hi);
    }
    if (idx < L_LAYERS * 256 * 256) {
        float f = gat_W[idx];
        __bf16 hi = (__bf16)f;
        Whi[idx] = hi;
        Wlo[idx] = (__bf16)(f - (float)hi);
    }
}

// x [M][49] fp32 -> xhi/xlo [M][64] bf16 (zero-padded)
__global__ void convert_x(const float* __restrict__ x,
                          __bf16* __restrict__ xhi, __bf16* __restrict__ xlo)
{
    int idx = blockIdx.x * 256 + threadIdx.x;   // M*64
    int m = idx >> 6, k = idx & 63;
    float f = (k < FIN) ? x[m * FIN + k] : 0.f;
    __bf16 hi = (__bf16)f;
    xhi[idx] = hi;
    xlo[idx] = (__bf16)(f - (float)hi);
}

// ---------------------------------------------------------------------------
// Embed GEMM: C[M,256] = A[M,64] @ B^T, 3-term bf16-split MFMA.
// BM=128, BN=128, BK=32, 256 thr (2x2 waves). (Round-3-verified kernel.)
// ---------------------------------------------------------------------------
template<bool A_BF16>
__global__ __launch_bounds__(256, 2)
void gemm_mfma(const float* __restrict__ Af32,
               const __bf16* __restrict__ Ahi, const __bf16* __restrict__ Alo,
               int K,
               const __bf16* __restrict__ Bhi, const __bf16* __restrict__ Blo,
               const float* __restrict__ bias,
               float* __restrict__ C)
{
    __shared__ __align__(16) char lds[2][32768];

    const int tid  = threadIdx.x;
    const int m0   = blockIdx.x * 128;
    const int n0   = blockIdx.y * 128;
    const int lane = tid & 63;
    const int wid  = tid >> 6;
    const int wr   = wid >> 1, wc = wid & 1;
    const int KSTEPS = K >> 5;

    float4 regA[2][2];
    bf16x8 regAh[2], regAl[2];
    bf16x8 regBh[2], regBl[2];

    f32x4 acc[4][4];
#pragma unroll
    for (int i = 0; i < 4; i++)
#pragma unroll
        for (int j = 0; j < 4; j++) acc[i][j] = (f32x4){0.f, 0.f, 0.f, 0.f};

    auto load_stage = [&](int k0) {
#pragma unroll
        for (int g = 0; g < 2; g++) {
            int u = g * 256 + tid, r = u >> 2, s = u & 3;
            if (A_BF16) {
                regAh[g] = *(const bf16x8*)(Ahi + (size_t)(m0 + r) * K + k0 + s * 8);
                regAl[g] = *(const bf16x8*)(Alo + (size_t)(m0 + r) * K + k0 + s * 8);
            } else {
                const float* ap = Af32 + (size_t)(m0 + r) * K + k0 + s * 8;
                regA[g][0] = *(const float4*)ap;
                regA[g][1] = *(const float4*)(ap + 4);
            }
            regBh[g] = *(const bf16x8*)(Bhi + (size_t)(n0 + r) * K + k0 + s * 8);
            regBl[g] = *(const bf16x8*)(Blo + (size_t)(n0 + r) * K + k0 + s * 8);
        }
    };

    auto write_stage = [&](int buf) {
        char* base = lds[buf];
#pragma unroll
        for (int g = 0; g < 2; g++) {
            int u = g * 256 + tid, r = u >> 2, s = u & 3;
            int off = swz(r, s);
            bf16x8 h8, l8;
            if (A_BF16) {
                h8 = regAh[g];
                l8 = regAl[g];
            } else {
                float fv[8] = {regA[g][0].x, regA[g][0].y, regA[g][0].z, regA[g][0].w,
                               regA[g][1].x, regA[g][1].y, regA[g][1].z, regA[g][1].w};
#pragma unroll
                for (int j = 0; j < 8; j++) {
                    __bf16 hi = (__bf16)fv[j];
                    h8[j] = hi;
                    l8[j] = (__bf16)(fv[j] - (float)hi);
                }
            }
            *(bf16x8*)(base + off)         = h8;
            *(bf16x8*)(base + 8192 + off)  = l8;
            *(bf16x8*)(base + 16384 + off) = regBh[g];
            *(bf16x8*)(base + 24576 + off) = regBl[g];
        }
    };

    auto compute = [&](int buf) {
        const char* base = lds[buf];
        const int s = lane >> 4;
        bf16x8 ah[4], al[4];
#pragma unroll
        for (int mf = 0; mf < 4; mf++) {
            int r = wr * 64 + mf * 16 + (lane & 15);
            int off = swz(r, s);
            ah[mf] = *(const bf16x8*)(base + off);
            al[mf] = *(const bf16x8*)(base + 8192 + off);
        }
#pragma unroll
        for (int nf = 0; nf < 4; nf++) {
            int r = wc * 64 + nf * 16 + (lane & 15);
            int off = swz(r, s);
            bf16x8 bh = *(const bf16x8*)(base + 16384 + off);
            bf16x8 bl = *(const bf16x8*)(base + 24576 + off);
#pragma unroll
            for (int mf = 0; mf < 4; mf++) {
                acc[mf][nf] = MFMA16(ah[mf], bh, acc[mf][nf]);
                acc[mf][nf] = MFMA16(ah[mf], bl, acc[mf][nf]);
                acc[mf][nf] = MFMA16(al[mf], bh, acc[mf][nf]);
            }
        }
    };

    load_stage(0);
    write_stage(0);
    if (KSTEPS > 1) load_stage(32);
    __syncthreads();

    for (int ks = 0; ks < KSTEPS; ks++) {
        compute(ks & 1);
        if (ks + 1 < KSTEPS) {
            write_stage((ks + 1) & 1);
            if (ks + 2 < KSTEPS) load_stage((ks + 2) << 5);
        }
        __syncthreads();
    }

#pragma unroll
    for (int nf = 0; nf < 4; nf++) {
        int col = n0 + wc * 64 + nf * 16 + (lane & 15);
        float bv = bias ? bias[col] : 0.f;
#pragma unroll
        for (int mf = 0; mf < 4; mf++) {
            int rbase = m0 + wr * 64 + mf * 16 + (lane >> 4) * 4;
#pragma unroll
            for (int rr = 0; rr < 4; rr++)
                C[(size_t)(rbase + rr) * 256 + col] = acc[mf][nf][rr] + bv;
        }
    }
}

// ---------------------------------------------------------------------------
// Fused layer: projection GEMM (128 rows = 2 graphs, K=256, N=256) + GAT
// attention, hp kept entirely in LDS. h updated in place.
//
// LDS map (74752 B):
//   GEMM stage (dead after GEMM): Ahi@0(8K) Alo@8192 Bhi@16384(16K) Blo@32768(16K)
//   attn: hp f32[64][256] @0 (64K, aliases stage)
//   persistent: Am u64[128]@65536  a f32[512]@66560  es f32[8][64]@68608
//               ed@70656  inv@72704
// ---------------------------------------------------------------------------
__global__ __launch_bounds__(256, 2)
void fused_gat_layer(const float* __restrict__ Amat,
                     float* __restrict__ h,
                     const __bf16* __restrict__ Whi, const __bf16* __restrict__ Wlo,
                     const float* __restrict__ bias,
                     const float* __restrict__ a_vec)
{
    __shared__ __align__(16) char smem[74752];
    float* lds_hp = (float*)smem;
    unsigned long long* lds_Am = (unsigned long long*)(smem + 65536);
    float* lds_a   = (float*)(smem + 66560);
    float* lds_es  = (float*)(smem + 68608);
    float* lds_ed  = (float*)(smem + 70656);
    float* lds_inv = (float*)(smem + 72704);

    const int tid  = threadIdx.x;
    const int lane = tid & 63;
    const int wid  = tid >> 6;
    const int wr   = wid >> 1, wc = wid & 1;
    const size_t m0 = (size_t)blockIdx.x * 128;

    // stage a_vec + adjacency bitmasks (visible after first GEMM barrier)
    lds_a[tid]       = a_vec[tid];
    lds_a[tid + 256] = a_vec[tid + 256];
    {
        const float* Ab = Amat + m0 * 64;          // 128 rows x 64
        for (int rr = 0; rr < 32; rr++) {
            int r = wid * 32 + rr;
            unsigned long long mk = __ballot(Ab[r * 64 + lane] > 0.f);
            if (lane == 0) lds_Am[r] = mk;
        }
    }

    // ---------------- GEMM phase: hp(regs) = h @ W^T ----------------
    f32x4 acc[4][8];
#pragma unroll
    for (int i = 0; i < 4; i++)
#pragma unroll
        for (int j = 0; j < 8; j++) acc[i][j] = (f32x4){0.f, 0.f, 0.f, 0.f};

    float4 rA[2][2];
    bf16x8 rBh[4], rBl[4];

    auto g_load = [&](int k0) {
#pragma unroll
        for (int g = 0; g < 2; g++) {
            int u = g * 256 + tid, r = u >> 2, s = u & 3;
            const float* ap = h + (m0 + r) * 256 + k0 + s * 8;
            rA[g][0] = *(const float4*)ap;
            rA[g][1] = *(const float4*)(ap + 4);
        }
#pragma unroll
        for (int g = 0; g < 4; g++) {
            int u = g * 256 + tid, r = u >> 2, s = u & 3;
            rBh[g] = *(const bf16x8*)(Whi + (size_t)r * 256 + k0 + s * 8);
            rBl[g] = *(const bf16x8*)(Wlo + (size_t)r * 256 + k0 + s * 8);
        }
    };

    auto s_write = [&]() {
#pragma unroll
        for (int g = 0; g < 2; g++) {
            int u = g * 256 + tid, r = u >> 2, s = u & 3;
            int off = swz(r, s);
            float fv[8] = {rA[g][0].x, rA[g][0].y, rA[g][0].z, rA[g][0].w,
                           rA[g][1].x, rA[g][1].y, rA[g][1].z, rA[g][1].w};
            bf16x8 h8, l8;
#pragma unroll
            for (int j = 0; j < 8; j++) {
                __bf16 hi = (__bf16)fv[j];
                h8[j] = hi;
                l8[j] = (__bf16)(fv[j] - (float)hi);
            }
            *(bf16x8*)(smem + off)        = h8;
            *(bf16x8*)(smem + 8192 + off) = l8;
        }
#pragma unroll
        for (int g = 0; g < 4; g++) {
            int u = g * 256 + tid, r = u >> 2, s = u & 3;
            int off = swz(r, s);
            *(bf16x8*)(smem + 16384 + off) = rBh[g];
            *(bf16x8*)(smem + 32768 + off) = rBl[g];
        }
    };

    auto s_compute = [&]() {
        const int s = lane >> 4;
        bf16x8 ah[4], al[4];
#pragma unroll
        for (int mf = 0; mf < 4; mf++) {
            int r = wr * 64 + mf * 16 + (lane & 15);
            int off = swz(r, s);
            ah[mf] = *(const bf16x8*)(smem + off);
            al[mf] = *(const bf16x8*)(smem + 8192 + off);
        }
#pragma unroll
        for (int nf = 0; nf < 8; nf++) {
            int r = wc * 128 + nf * 16 + (lane & 15);
            int off = swz(r, s);
            bf16x8 bh = *(const bf16x8*)(smem + 16384 + off);
            bf16x8 bl = *(const bf16x8*)(smem + 32768 + off);
#pragma unroll
            for (int mf = 0; mf < 4; mf++) {
                acc[mf][nf] = MFMA16(ah[mf], bh, acc[mf][nf]);
                acc[mf][nf] = MFMA16(ah[mf], bl, acc[mf][nf]);
                acc[mf][nf] = MFMA16(al[mf], bh, acc[mf][nf]);
            }
        }
    };

    g_load(0);
    for (int ks = 0; ks < 8; ks++) {
        __syncthreads();
        s_write();
        __syncthreads();
        if (ks < 7) g_load((ks + 1) * 32);
        s_compute();
    }

    // ---------------- attention phases ----------------
    auto write_hp = [&]() {
#pragma unroll
        for (int nf = 0; nf < 8; nf++) {
            int c = wc * 128 + nf * 16 + (lane & 15);
            float bv = bias[c];
#pragma unroll
            for (int mf = 0; mf < 4; mf++) {
                int i = mf * 16 + (lane >> 4) * 4;
#pragma unroll
                for (int rr = 0; rr < 4; rr++)
                    lds_hp[(i + rr) * 256 + c] = acc[mf][nf][rr] + bv;
            }
        }
    };

    auto attn_compute = [&](int g) {
        float emax[4];
        // e_src/e_dst for this wave's 4 heads; node = lane
#pragma unroll
        for (int hl = 0; hl < 4; hl++) {
            int head = wc * 4 + hl;
            float es = 0.f, ed = 0.f;
#pragma unroll
            for (int cc = 0; cc < 8; cc++) {
                int ss = (cc + lane) & 7;
                float4 hv = *(const float4*)&lds_hp[lane * 256 + head * 32 + ss * 4];
                float4 as = *(const float4*)&lds_a[head * 64 + ss * 4];
                float4 ad = *(const float4*)&lds_a[head * 64 + 32 + ss * 4];
                es += hv.x * as.x + hv.y * as.y + hv.z * as.z + hv.w * as.w;
                ed += hv.x * ad.x + hv.y * ad.y + hv.z * ad.z + hv.w * ad.w;
            }
            lds_es[head * 64 + lane] = es;
            lds_ed[head * 64 + lane] = ed;
            float v = ed;
#pragma unroll
            for (int off = 32; off; off >>= 1) v = fmaxf(v, __shfl_xor(v, off));
            emax[hl] = v;
        }

#pragma unroll
        for (int hl = 0; hl < 4; hl++) {
            int head = wc * 4 + hl;
            f32x4 pv[4][2];
#pragma unroll
            for (int mf = 0; mf < 4; mf++)
#pragma unroll
                for (int nf = 0; nf < 2; nf++) pv[mf][nf] = (f32x4){0.f, 0.f, 0.f, 0.f};
            float rs[4] = {0.f, 0.f, 0.f, 0.f};

            float esi[4], mh[4];
            unsigned long long msk_i[4];
#pragma unroll
            for (int mf = 0; mf < 4; mf++) {
                int i = mf * 16 + (lane & 15);
                esi[mf] = lds_es[head * 64 + i];
                float t = esi[mf] + emax[hl];
                mh[mf] = t > 0.f ? t : ALPHA * t;
                msk_i[mf] = lds_Am[g * 64 + i];
            }

#pragma unroll
            for (int ksj = 0; ksj < 2; ksj++) {
                int j8 = ksj * 32 + (lane >> 4) * 8;
                // V fragments (B operand) hi/lo from lds_hp
                bf16x8 bh[2], bl[2];
#pragma unroll
                for (int nf = 0; nf < 2; nf++) {
                    int d = head * 32 + nf * 16 + (lane & 15);
#pragma unroll
                    for (int e = 0; e < 8; e++) {
                        float v = lds_hp[(j8 + e) * 256 + d];
                        __bf16 hi = (__bf16)v;
                        bh[nf][e] = hi;
                        bl[nf][e] = (__bf16)(v - (float)hi);
                    }
                }
                float4 e0 = *(const float4*)&lds_ed[head * 64 + j8];
                float4 e1 = *(const float4*)&lds_ed[head * 64 + j8 + 4];
                float edv[8] = {e0.x, e0.y, e0.z, e0.w, e1.x, e1.y, e1.z, e1.w};
#pragma unroll
                for (int mf = 0; mf < 4; mf++) {
                    unsigned int mb = (unsigned int)(msk_i[mf] >> j8) & 0xffu;
                    bf16x8 ph, pl;
                    float rsum = 0.f;
#pragma unroll
                    for (int e = 0; e < 8; e++) {
                        float ev = esi[mf] + edv[e];
                        ev = ev > 0.f ? ev : ALPHA * ev;
                        float p = ((mb >> e) & 1u) ? __expf(ev - mh[mf]) : 0.f;
                        rsum += p;
                        __bf16 hi = (__bf16)p;
                        ph[e] = hi;
                        pl[e] = (__bf16)(p - (float)hi);
                    }
                    rs[mf] += rsum;
#pragma unroll
                    for (int nf = 0; nf < 2; nf++) {
                        pv[mf][nf] = MFMA16(ph, bh[nf], pv[mf][nf]);
                        pv[mf][nf] = MFMA16(ph, bl[nf], pv[mf][nf]);
                        pv[mf][nf] = MFMA16(pl, bh[nf], pv[mf][nf]);
                    }
                }
            }

            // row sums -> inv (rows i = mf*16 + (lane&15), j-partials across l>>4)
#pragma unroll
            for (int mf = 0; mf < 4; mf++) {
                float r = rs[mf];
                r += __shfl_xor(r, 16);
                r += __shfl_xor(r, 32);
                if ((lane >> 4) == 0)
                    lds_inv[head * 64 + mf * 16 + lane] = (r > 0.f) ? 1.f / r : 0.f;
            }

            // epilogue: scale, residual, ELU, store
            size_t grow = m0 + (size_t)g * 64;
#pragma unroll
            for (int mf = 0; mf < 4; mf++) {
#pragma unroll
                for (int nf = 0; nf < 2; nf++) {
                    int d = head * 32 + nf * 16 + (lane & 15);
#pragma unroll
                    for (int rr = 0; rr < 4; rr++) {
                        int i = mf * 16 + (lane >> 4) * 4 + rr;
                        float inv = lds_inv[head * 64 + i];
                        float* hrow = &h[(grow + i) * 256 + d];
                        float o = pv[mf][nf][rr] * inv + *hrow;
                        *hrow = o > 0.f ? o : __expf(o) - 1.f;
                    }
                }
            }
        }
    };

    __syncthreads();                 // GEMM stage dead; hp region free
    if (wr == 0) write_hp();
    __syncthreads();
    if (wr == 0) attn_compute(0);
    __syncthreads();
    if (wr == 1) write_hp();
    __syncthreads();
    if (wr == 1) attn_compute(1);
}

// ---------------------------------------------------------------------------
// Masked mean-pool + 3-layer MLP + elu + 1.5. One block per graph.
// ---------------------------------------------------------------------------
__global__ __launch_bounds__(256)
void pool_mlp(const float* __restrict__ Amat, const float* __restrict__ h,
              const float* __restrict__ W1, const float* __restrict__ b1,
              const float* __restrict__ W2, const float* __restrict__ b2,
              const float* __restrict__ W3, const float* __restrict__ b3,
              float* __restrict__ out)
{
    __shared__ float lds_g[256];
    __shared__ float lds_z1[128];
    __shared__ float lds_z2[128];
    __shared__ unsigned long long lds_m;
    __shared__ float lds_invcnt;

    const int tid = threadIdx.x;
    const int b   = blockIdx.x;
    const float* Ab = Amat + (size_t)b * 4096;
    const float* hb = h    + (size_t)b * 16384;

    if (tid < 64) {
        float dv = Ab[tid * 64 + tid];
        unsigned long long m = __ballot(dv > 0.f);
        if (tid == 0) { lds_m = m; lds_invcnt = 1.f / (float)__popcll(m); }
    }
    __syncthreads();

    unsigned long long msk = lds_m;
    float invc = lds_invcnt;
    float g = 0.f;
    for (int n = 0; n < 64; n++)
        if ((msk >> n) & 1ULL) g += hb[n * 256 + tid];
    lds_g[tid] = g * invc;
    __syncthreads();

    if (tid < 128) {
        const float* wr = W1 + tid * 256;
        float z = 0.f;
#pragma unroll 8
        for (int k = 0; k < 256; k += 4) {
            float4 wv = *(const float4*)&wr[k];
            z += wv.x * lds_g[k] + wv.y * lds_g[k + 1] + wv.z * lds_g[k + 2] + wv.w * lds_g[k + 3];
        }
        z += b1[tid];
        lds_z1[tid] = z > 0.f ? z : 0.f;
    }
    __syncthreads();

    if (tid < 128) {
        const float* wr = W2 + tid * 128;
        float z = 0.f;
#pragma unroll 8
        for (int k = 0; k < 128; k += 4) {
            float4 wv = *(const float4*)&wr[k];
            z += wv.x * lds_z1[k] + wv.y * lds_z1[k + 1] + wv.z * lds_z1[k + 2] + wv.w * lds_z1[k + 3];
        }
        z += b2[tid];
        lds_z2[tid] = z > 0.f ? z : 0.f;
    }
    __syncthreads();

    if (tid < 64) {
        float p = W3[tid] * lds_z2[tid] + W3[tid + 64] * lds_z2[tid + 64];
        for (int off = 32; off; off >>= 1) p += __shfl_down(p, off);
        if (tid == 0) {
            float z = p + b3[0];
            out[b] = (z > 0.f ? z : __expf(z) - 1.f) + 1.5f;
        }
    }
}

// ---------------------------------------------------------------------------
extern "C" void kernel_launch(void* const* d_in, const int* in_sizes, int n_in,
                              void* d_out, int out_size, void* d_ws, size_t ws_size,
                              hipStream_t stream)
{
    const float* x      = (const float*)d_in[0];
    const float* A      = (const float*)d_in[1];
    const float* W_emb  = (const float*)d_in[2];
    const float* gat_W  = (const float*)d_in[3];
    const float* gat_b  = (const float*)d_in[4];
    const float* gat_a  = (const float*)d_in[5];
    const float* fc_W1  = (const float*)d_in[6];
    const float* fc_b1  = (const float*)d_in[7];
    const float* fc_W2  = (const float*)d_in[8];
    const float* fc_b2  = (const float*)d_in[9];
    const float* fc_W3  = (const float*)d_in[10];
    const float* fc_b3  = (const float*)d_in[11];
    float* out = (float*)d_out;

    // workspace (~161.6 MB):
    //   h fp32 [131072][256]        @ 0            134217728
    //   xhi/xlo bf16 [131072][64]   @ 134217728    2 x 16777216
    //   Whi_emb/Wlo_emb [256][64]   @ 167772160    2 x 32768
    //   Whi/Wlo [6][256][256]       @ 167837696    2 x 786432
    char* ws = (char*)d_ws;
    float*  h       = (float*)ws;
    __bf16* xhi     = (__bf16*)(ws + 134217728);
    __bf16* xlo     = (__bf16*)(ws + 134217728 + 16777216);
    __bf16* Whi_emb = (__bf16*)(ws + 167772160);
    __bf16* Wlo_emb = (__bf16*)(ws + 167772160 + 32768);
    __bf16* Whi     = (__bf16*)(ws + 167837696);
    __bf16* Wlo     = (__bf16*)(ws + 167837696 + 786432);

    convert_weights<<<1536, 256, 0, stream>>>(W_emb, gat_W, Whi_emb, Wlo_emb, Whi, Wlo);
    convert_x<<<M_FULL * 64 / 256, 256, 0, stream>>>(x, xhi, xlo);

    // embed: h = x @ W_emb.T   (M=131072, K=64 padded)
    gemm_mfma<true><<<dim3(M_FULL / 128, 2), 256, 0, stream>>>(
        nullptr, xhi, xlo, 64, Whi_emb, Wlo_emb, nullptr, h);

    for (int l = 0; l < L_LAYERS; l++) {
        fused_gat_layer<<<M_FULL / 128, 256, 0, stream>>>(
            A, h,
            Whi + (size_t)l * 65536, Wlo + (size_t)l * 65536,
            gat_b + l * D_DIM,
            gat_a + l * H_HEADS * 2 * DK_DIM);
    }

    pool_mlp<<<B_GRAPHS, 256, 0, stream>>>(A, h, fc_W1, fc_b1, fc_W2, fc_b2,
                                           fc_W3, fc_b3, out);
}

// Round 5
// 1627.349 us; speedup vs baseline: 1.5372x; 1.5372x over previous
//
#include <hip/hip_runtime.h>
#include <cstdint>
#include <cstddef>

#define B_GRAPHS 2048
#define N_NODES  64
#define FIN      49
#define D_DIM    256
#define H_HEADS  8
#define DK_DIM   32
#define L_LAYERS 6
#define ALPHA    0.2f

#define M_FULL     (B_GRAPHS * N_NODES)           // 131072 rows
#define WROWS      272                             // 256 W rows + 16 Wa rows
#define WSLAB      (WROWS * 256)                   // per-layer weight slab elems

typedef __bf16 bf16x8 __attribute__((ext_vector_type(8)));
typedef __bf16 bf16x4 __attribute__((ext_vector_type(4)));
typedef float  f32x4  __attribute__((ext_vector_type(4)));

#define MFMA16(a, b, c) __builtin_amdgcn_mfma_f32_16x16x32_bf16(a, b, c, 0, 0, 0)

__device__ __forceinline__ float leaky(float t) { return t > 0.f ? t : ALPHA * t; }

// ---------------------------------------------------------------------------
// Weight prep: split W (+ append Wa = W^T a rows) to bf16 hi/lo; ba = b.a.
//   Whi/Wlo: [6][272][256]  rows 0..255 = W[n][k]; rows 256..271 = Wa[c][k],
//   c = 2h+sd (sd: 0=src,1=dst).  ba: [6][16] f32.
// ---------------------------------------------------------------------------
__global__ void convert_weights(const float* __restrict__ W_emb,
                                const float* __restrict__ gat_W,
                                const float* __restrict__ gat_a,
                                const float* __restrict__ gat_b,
                                __bf16* __restrict__ Whi_emb,
                                __bf16* __restrict__ Wlo_emb,
                                __bf16* __restrict__ Whi,
                                __bf16* __restrict__ Wlo,
                                float* __restrict__ ba)
{
    int idx = blockIdx.x * 256 + threadIdx.x;
    if (idx < 256 * 64) {
        int n = idx >> 6, k = idx & 63;
        float f = (k < FIN) ? W_emb[n * FIN + k] : 0.f;
        __bf16 hi = (__bf16)f;
        Whi_emb[idx] = hi;
        Wlo_emb[idx] = (__bf16)(f - (float)hi);
    }
    if (idx < L_LAYERS * 65536) {
        int l = idx >> 16, nk = idx & 65535;
        float f = gat_W[idx];
        __bf16 hi = (__bf16)f;
        int dst = l * WSLAB + nk;
        Whi[dst] = hi;
        Wlo[dst] = (__bf16)(f - (float)hi);
    }
    int o = idx - L_LAYERS * 65536;
    if (o >= 0 && o < L_LAYERS * 4096) {
        int l = o >> 12, r = o & 4095;
        int k = r >> 4, c = r & 15;
        int hh = c >> 1, sd = c & 1;
        const float* av = gat_a + l * 512 + hh * 64 + sd * 32;
        const float* wp = gat_W + ((size_t)l * 256 + hh * 32) * 256 + k;
        float s = 0.f;
        for (int d = 0; d < 32; d++) s += av[d] * wp[d * 256];
        int dst = l * WSLAB + (256 + c) * 256 + k;
        __bf16 hi = (__bf16)s;
        Whi[dst] = hi;
        Wlo[dst] = (__bf16)(s - (float)hi);
    }
    int o2 = idx - L_LAYERS * 65536 - L_LAYERS * 4096;
    if (o2 >= 0 && o2 < L_LAYERS * 16) {
        int l = o2 >> 4, c = o2 & 15;
        int hh = c >> 1, sd = c & 1;
        const float* av = gat_a + l * 512 + hh * 64 + sd * 32;
        const float* bp = gat_b + l * 256 + hh * 32;
        float s = 0.f;
        for (int d = 0; d < 32; d++) s += av[d] * bp[d];
        ba[o2] = s;
    }
}

// x [M][49] fp32 -> xhi/xlo [M][64] bf16 (zero-padded)
__global__ void convert_x(const float* __restrict__ x,
                          __bf16* __restrict__ xhi, __bf16* __restrict__ xlo)
{
    int idx = blockIdx.x * 256 + threadIdx.x;
    int m = idx >> 6, k = idx & 63;
    float f = (k < FIN) ? x[m * FIN + k] : 0.f;
    __bf16 hi = (__bf16)f;
    xhi[idx] = hi;
    xlo[idx] = (__bf16)(f - (float)hi);
}

// ---------------------------------------------------------------------------
// Embed GEMM (round-3-verified): C[M,256] = A[M,64] @ B^T, 3-term bf16 split.
// ---------------------------------------------------------------------------
__device__ __forceinline__ int swz(int r, int s) {
    return r * 64 + (((s ^ (r & 3)) << 4));
}

__global__ __launch_bounds__(256, 2)
void gemm_embed(const __bf16* __restrict__ Ahi, const __bf16* __restrict__ Alo,
                const __bf16* __restrict__ Bhi, const __bf16* __restrict__ Blo,
                float* __restrict__ C)
{
    const int K = 64;
    __shared__ __align__(16) char lds[2][32768];

    const int tid  = threadIdx.x;
    const int m0   = blockIdx.x * 128;
    const int n0   = blockIdx.y * 128;
    const int lane = tid & 63;
    const int wid  = tid >> 6;
    const int wr   = wid >> 1, wc = wid & 1;

    bf16x8 regAh[2], regAl[2], regBh[2], regBl[2];
    f32x4 acc[4][4];
#pragma unroll
    for (int i = 0; i < 4; i++)
#pragma unroll
        for (int j = 0; j < 4; j++) acc[i][j] = (f32x4){0.f, 0.f, 0.f, 0.f};

    auto load_stage = [&](int k0) {
#pragma unroll
        for (int g = 0; g < 2; g++) {
            int u = g * 256 + tid, r = u >> 2, s = u & 3;
            regAh[g] = *(const bf16x8*)(Ahi + (size_t)(m0 + r) * K + k0 + s * 8);
            regAl[g] = *(const bf16x8*)(Alo + (size_t)(m0 + r) * K + k0 + s * 8);
            regBh[g] = *(const bf16x8*)(Bhi + (size_t)(n0 + r) * K + k0 + s * 8);
            regBl[g] = *(const bf16x8*)(Blo + (size_t)(n0 + r) * K + k0 + s * 8);
        }
    };
    auto write_stage = [&](int buf) {
        char* base = lds[buf];
#pragma unroll
        for (int g = 0; g < 2; g++) {
            int u = g * 256 + tid, r = u >> 2, s = u & 3;
            int off = swz(r, s);
            *(bf16x8*)(base + off)         = regAh[g];
            *(bf16x8*)(base + 8192 + off)  = regAl[g];
            *(bf16x8*)(base + 16384 + off) = regBh[g];
            *(bf16x8*)(base + 24576 + off) = regBl[g];
        }
    };
    auto compute = [&](int buf) {
        const char* base = lds[buf];
        const int s = lane >> 4;
        bf16x8 ah[4], al[4];
#pragma unroll
        for (int mf = 0; mf < 4; mf++) {
            int r = wr * 64 + mf * 16 + (lane & 15);
            int off = swz(r, s);
            ah[mf] = *(const bf16x8*)(base + off);
            al[mf] = *(const bf16x8*)(base + 8192 + off);
        }
#pragma unroll
        for (int nf = 0; nf < 4; nf++) {
            int r = wc * 64 + nf * 16 + (lane & 15);
            int off = swz(r, s);
            bf16x8 bh = *(const bf16x8*)(base + 16384 + off);
            bf16x8 bl = *(const bf16x8*)(base + 24576 + off);
#pragma unroll
            for (int mf = 0; mf < 4; mf++) {
                acc[mf][nf] = MFMA16(ah[mf], bh, acc[mf][nf]);
                acc[mf][nf] = MFMA16(ah[mf], bl, acc[mf][nf]);
                acc[mf][nf] = MFMA16(al[mf], bh, acc[mf][nf]);
            }
        }
    };

    load_stage(0);
    write_stage(0);
    load_stage(32);
    __syncthreads();
    compute(0);
    write_stage(1);
    __syncthreads();
    compute(1);

#pragma unroll
    for (int nf = 0; nf < 4; nf++) {
        int col = n0 + wc * 64 + nf * 16 + (lane & 15);
#pragma unroll
        for (int mf = 0; mf < 4; mf++) {
            int rbase = m0 + wr * 64 + mf * 16 + (lane >> 4) * 4;
#pragma unroll
            for (int rr = 0; rr < 4; rr++)
                C[(size_t)(rbase + rr) * 256 + col] = acc[mf][nf][rr];
        }
    }
}

// ---------------------------------------------------------------------------
// Fused GAT layer v2: one graph per block, 4 waves, each wave fully owns a
// 64-col slice = 2 heads.  B (weights+Wa) streamed from L2, A-frags from
// global, V + E in wave-private LDS, exactly ONE barrier (WAR on h).
//
// Per-wave LDS (17664 B): Vf [2 hl][hi/lo 4KB][32 d][64 j] bf16 swizzled @0,
//   E f32 [4 c'][64 j] @16384, inv f32 [64] @17408.
// ---------------------------------------------------------------------------
__global__ __launch_bounds__(256, 2)
void fused_gat_layer(const float* __restrict__ Amat,
                     float* h,
                     const __bf16* __restrict__ Whi, const __bf16* __restrict__ Wlo,
                     const float* __restrict__ bias,
                     const float* __restrict__ ba)
{
    __shared__ __align__(16) char smem[4 * 17664];

    const int tid  = threadIdx.x;
    const int lane = tid & 63;
    const int w    = tid >> 6;
    const int q    = lane >> 4;
    const int d15  = lane & 15;
    const int g    = blockIdx.x;
    const size_t m0 = (size_t)g * 64;

    char*  wbase = smem + w * 17664;
    float* E     = (float*)(wbase + 16384);
    float* invv  = (float*)(wbase + 17408);

    // --- adjacency masks: msk[mf] = row (mf*16 + d15) bitmask ---
    unsigned long long msk[4] = {0ull, 0ull, 0ull, 0ull};
    {
        const float* Ab = Amat + (size_t)g * 4096;
#pragma unroll
        for (int r = 0; r < 64; r++) {
            unsigned long long bal = __ballot(Ab[r * 64 + lane] > 0.f);
            if ((r & 15) == d15) msk[r >> 4] = bal;
        }
    }

    // --- GEMM: acc[mf][nf] = hp tile, accE[mf] = es/ed tile ---
    f32x4 acc[4][4], accE[4];
#pragma unroll
    for (int i = 0; i < 4; i++) {
        accE[i] = (f32x4){0.f, 0.f, 0.f, 0.f};
#pragma unroll
        for (int j = 0; j < 4; j++) acc[i][j] = (f32x4){0.f, 0.f, 0.f, 0.f};
    }

#pragma unroll 2
    for (int ks = 0; ks < 8; ks++) {
        const int k0 = ks * 32 + q * 8;
        bf16x8 ah[4], al[4];
#pragma unroll
        for (int mf = 0; mf < 4; mf++) {
            const float* ap = h + (m0 + mf * 16 + d15) * 256 + k0;
            float4 x0 = *(const float4*)ap;
            float4 x1 = *(const float4*)(ap + 4);
            float fv[8] = {x0.x, x0.y, x0.z, x0.w, x1.x, x1.y, x1.z, x1.w};
#pragma unroll
            for (int e = 0; e < 8; e++) {
                __bf16 hb = (__bf16)fv[e];
                ah[mf][e] = hb;
                al[mf][e] = (__bf16)(fv[e] - (float)hb);
            }
        }
#pragma unroll
        for (int nt = 0; nt < 5; nt++) {
            int n = (nt < 4) ? (w * 64 + nt * 16 + d15) : (256 + d15);
            bf16x8 bh = *(const bf16x8*)(Whi + (size_t)n * 256 + k0);
            bf16x8 bl = *(const bf16x8*)(Wlo + (size_t)n * 256 + k0);
            if (nt < 4) {
#pragma unroll
                for (int mf = 0; mf < 4; mf++) {
                    acc[mf][nt] = MFMA16(ah[mf], bh, acc[mf][nt]);
                    acc[mf][nt] = MFMA16(ah[mf], bl, acc[mf][nt]);
                    acc[mf][nt] = MFMA16(al[mf], bh, acc[mf][nt]);
                }
            } else {
#pragma unroll
                for (int mf = 0; mf < 4; mf++) {
                    accE[mf] = MFMA16(ah[mf], bh, accE[mf]);
                    accE[mf] = MFMA16(ah[mf], bl, accE[mf]);
                    accE[mf] = MFMA16(al[mf], bh, accE[mf]);
                }
            }
        }
    }

    // All h A-reads (every wave) must complete before any epilogue h-write.
    __syncthreads();

    // --- write V fragments (wave-private, swizzled [d][j] hi/lo) + bias ---
#pragma unroll
    for (int nf = 0; nf < 4; nf++) {
        const int hl = nf >> 1;
        const int d  = (nf & 1) * 16 + d15;
        const float bv = bias[w * 64 + nf * 16 + d15];
        char* vb = wbase + hl * 8192 + d * 128;
#pragma unroll
        for (int mf = 0; mf < 4; mf++) {
            int s   = mf * 2 + (q >> 1);
            int off = ((s ^ (d & 7)) << 4) + (q & 1) * 8;
            bf16x4 h4, l4;
#pragma unroll
            for (int rr = 0; rr < 4; rr++) {
                float v = acc[mf][nf][rr] + bv;
                __bf16 hb = (__bf16)v;
                h4[rr] = hb;
                l4[rr] = (__bf16)(v - (float)hb);
            }
            *(bf16x4*)(vb + off)        = h4;
            *(bf16x4*)(vb + 4096 + off) = l4;
        }
    }

    // --- write E (es/ed for this wave's heads): cols 4w..4w+3 ---
    if (d15 >= 4 * w && d15 < 4 * w + 4) {
        const int cl = d15 - 4 * w;
        const float bav = ba[d15];
#pragma unroll
        for (int mf = 0; mf < 4; mf++)
#pragma unroll
            for (int rr = 0; rr < 4; rr++)
                E[cl * 64 + mf * 16 + q * 4 + rr] = accE[mf][rr] + bav;
    }

    // --- attention: 2 heads per wave, all in-wave ---
#pragma unroll
    for (int hl = 0; hl < 2; hl++) {
        const int head = 2 * w + hl;

        float ev = E[(hl * 2 + 1) * 64 + lane];
#pragma unroll
        for (int off = 32; off; off >>= 1) ev = fmaxf(ev, __shfl_xor(ev, off));

        float esi[4], mh[4];
#pragma unroll
        for (int mf = 0; mf < 4; mf++) {
            esi[mf] = E[(hl * 2) * 64 + mf * 16 + d15];
            mh[mf]  = leaky(esi[mf] + ev);
        }

        f32x4 pv[4][2];
#pragma unroll
        for (int mf = 0; mf < 4; mf++) {
            pv[mf][0] = (f32x4){0.f, 0.f, 0.f, 0.f};
            pv[mf][1] = (f32x4){0.f, 0.f, 0.f, 0.f};
        }
        float rs[4] = {0.f, 0.f, 0.f, 0.f};

#pragma unroll
        for (int ksj = 0; ksj < 2; ksj++) {
            const int j8 = ksj * 32 + q * 8;
            const int s  = ksj * 4 + q;
            bf16x8 vh[2], vl[2];
#pragma unroll
            for (int nf2 = 0; nf2 < 2; nf2++) {
                int d = nf2 * 16 + d15;
                int off = hl * 8192 + d * 128 + ((s ^ (d & 7)) << 4);
                vh[nf2] = *(const bf16x8*)(wbase + off);
                vl[nf2] = *(const bf16x8*)(wbase + 4096 + off);
            }
            float edv[8];
#pragma unroll
            for (int e = 0; e < 8; e++) edv[e] = E[(hl * 2 + 1) * 64 + j8 + e];

#pragma unroll
            for (int mf = 0; mf < 4; mf++) {
                unsigned int mb = (unsigned int)(msk[mf] >> j8) & 0xffu;
                bf16x8 ph, pl;
                float rsum = 0.f;
#pragma unroll
                for (int e = 0; e < 8; e++) {
                    float t = leaky(esi[mf] + edv[e]);
                    float p = ((mb >> e) & 1u) ? __expf(t - mh[mf]) : 0.f;
                    rsum += p;
                    __bf16 hb = (__bf16)p;
                    ph[e] = hb;
                    pl[e] = (__bf16)(p - (float)hb);
                }
                rs[mf] += rsum;
#pragma unroll
                for (int nf2 = 0; nf2 < 2; nf2++) {
                    pv[mf][nf2] = MFMA16(ph, vh[nf2], pv[mf][nf2]);
                    pv[mf][nf2] = MFMA16(ph, vl[nf2], pv[mf][nf2]);
                    pv[mf][nf2] = MFMA16(pl, vh[nf2], pv[mf][nf2]);
                }
            }
        }

        // row-sum reduce across q groups; inv via wave-private LDS
#pragma unroll
        for (int mf = 0; mf < 4; mf++) {
            float r = rs[mf];
            r += __shfl_xor(r, 16);
            r += __shfl_xor(r, 32);
            if (q == 0) invv[mf * 16 + d15] = (r > 0.f) ? 1.f / r : 0.f;
        }

        // epilogue: scale, residual, ELU, store (wave-own cols only)
#pragma unroll
        for (int mf = 0; mf < 4; mf++) {
#pragma unroll
            for (int nf2 = 0; nf2 < 2; nf2++) {
                int d = head * 32 + nf2 * 16 + d15;
#pragma unroll
                for (int rr = 0; rr < 4; rr++) {
                    int i = mf * 16 + q * 4 + rr;
                    float inv = invv[i];
                    float* hp_ = &h[(m0 + i) * 256 + d];
                    float o = pv[mf][nf2][rr] * inv + *hp_;
                    *hp_ = o > 0.f ? o : __expf(o) - 1.f;
                }
            }
        }
    }
}

// ---------------------------------------------------------------------------
// Masked mean-pool + 3-layer MLP + elu + 1.5. One block per graph.
// ---------------------------------------------------------------------------
__global__ __launch_bounds__(256)
void pool_mlp(const float* __restrict__ Amat, const float* __restrict__ h,
              const float* __restrict__ W1, const float* __restrict__ b1,
              const float* __restrict__ W2, const float* __restrict__ b2,
              const float* __restrict__ W3, const float* __restrict__ b3,
              float* __restrict__ out)
{
    __shared__ float lds_g[256];
    __shared__ float lds_z1[128];
    __shared__ float lds_z2[128];
    __shared__ unsigned long long lds_m;
    __shared__ float lds_invcnt;

    const int tid = threadIdx.x;
    const int b   = blockIdx.x;
    const float* Ab = Amat + (size_t)b * 4096;
    const float* hb = h    + (size_t)b * 16384;

    if (tid < 64) {
        float dv = Ab[tid * 64 + tid];
        unsigned long long m = __ballot(dv > 0.f);
        if (tid == 0) { lds_m = m; lds_invcnt = 1.f / (float)__popcll(m); }
    }
    __syncthreads();

    unsigned long long msk = lds_m;
    float invc = lds_invcnt;
    float gsum = 0.f;
    for (int n = 0; n < 64; n++)
        if ((msk >> n) & 1ULL) gsum += hb[n * 256 + tid];
    lds_g[tid] = gsum * invc;
    __syncthreads();

    if (tid < 128) {
        const float* wr = W1 + tid * 256;
        float z = 0.f;
#pragma unroll 8
        for (int k = 0; k < 256; k += 4) {
            float4 wv = *(const float4*)&wr[k];
            z += wv.x * lds_g[k] + wv.y * lds_g[k + 1] + wv.z * lds_g[k + 2] + wv.w * lds_g[k + 3];
        }
        z += b1[tid];
        lds_z1[tid] = z > 0.f ? z : 0.f;
    }
    __syncthreads();

    if (tid < 128) {
        const float* wr = W2 + tid * 128;
        float z = 0.f;
#pragma unroll 8
        for (int k = 0; k < 128; k += 4) {
            float4 wv = *(const float4*)&wr[k];
            z += wv.x * lds_z1[k] + wv.y * lds_z1[k + 1] + wv.z * lds_z1[k + 2] + wv.w * lds_z1[k + 3];
        }
        z += b2[tid];
        lds_z2[tid] = z > 0.f ? z : 0.f;
    }
    __syncthreads();

    if (tid < 64) {
        float p = W3[tid] * lds_z2[tid] + W3[tid + 64] * lds_z2[tid + 64];
        for (int off = 32; off; off >>= 1) p += __shfl_down(p, off);
        if (tid == 0) {
            float z = p + b3[0];
            out[b] = (z > 0.f ? z : __expf(z) - 1.f) + 1.5f;
        }
    }
}

// ---------------------------------------------------------------------------
extern "C" void kernel_launch(void* const* d_in, const int* in_sizes, int n_in,
                              void* d_out, int out_size, void* d_ws, size_t ws_size,
                              hipStream_t stream)
{
    const float* x      = (const float*)d_in[0];
    const float* A      = (const float*)d_in[1];
    const float* W_emb  = (const float*)d_in[2];
    const float* gat_W  = (const float*)d_in[3];
    const float* gat_b  = (const float*)d_in[4];
    const float* gat_a  = (const float*)d_in[5];
    const float* fc_W1  = (const float*)d_in[6];
    const float* fc_b1  = (const float*)d_in[7];
    const float* fc_W2  = (const float*)d_in[8];
    const float* fc_b2  = (const float*)d_in[9];
    const float* fc_W3  = (const float*)d_in[10];
    const float* fc_b3  = (const float*)d_in[11];
    float* out = (float*)d_out;

    // workspace (~170 MB):
    //   h fp32 [131072][256]        @ 0            134217728
    //   xhi/xlo bf16 [131072][64]   @ 134217728    2 x 16777216
    //   Whi_emb/Wlo_emb [256][64]   @ 167772160    2 x 32768
    //   Whi [6][272][256] bf16      @ 167837696    835584
    //   Wlo                         @ 168673280    835584
    //   ba  [6][16] f32             @ 169508864    384
    char* ws = (char*)d_ws;
    float*  h       = (float*)ws;
    __bf16* xhi     = (__bf16*)(ws + 134217728);
    __bf16* xlo     = (__bf16*)(ws + 134217728 + 16777216);
    __bf16* Whi_emb = (__bf16*)(ws + 167772160);
    __bf16* Wlo_emb = (__bf16*)(ws + 167772160 + 32768);
    __bf16* Whi     = (__bf16*)(ws + 167837696);
    __bf16* Wlo     = (__bf16*)(ws + 168673280);
    float*  ba      = (float*)(ws + 169508864);

    int conv_total = 256 * 64;
    if (L_LAYERS * 65536 > conv_total) conv_total = L_LAYERS * 65536;
    conv_total = L_LAYERS * 65536 + L_LAYERS * 4096 + L_LAYERS * 16;
    convert_weights<<<(conv_total + 255) / 256, 256, 0, stream>>>(
        W_emb, gat_W, gat_a, gat_b, Whi_emb, Wlo_emb, Whi, Wlo, ba);
    convert_x<<<M_FULL * 64 / 256, 256, 0, stream>>>(x, xhi, xlo);

    gemm_embed<<<dim3(M_FULL / 128, 2), 256, 0, stream>>>(
        xhi, xlo, Whi_emb, Wlo_emb, h);

    for (int l = 0; l < L_LAYERS; l++) {
        fused_gat_layer<<<B_GRAPHS, 256, 0, stream>>>(
            A, h,
            Whi + (size_t)l * WSLAB, Wlo + (size_t)l * WSLAB,
            gat_b + l * D_DIM, ba + l * 16);
    }

    pool_mlp<<<B_GRAPHS, 256, 0, stream>>>(A, h, fc_W1, fc_b1, fc_W2, fc_b2,
                                           fc_W3, fc_b3, out);
}